// Round 5
// baseline (497.606 us; speedup 1.0000x reference)
//
#include <hip/hip_runtime.h>
#include <hip/hip_fp16.h>

namespace {
constexpr int kT = 32, kDQ = 128, kK = 8, kD = 257, kCTX = 16;
constexpr float kDT = 0.2f, kDAMP = 0.1f, kGAMMA = 10.0f, kEPS = 1e-8f;

typedef _Float16 half8 __attribute__((ext_vector_type(8)));
typedef _Float16 h2 __attribute__((ext_vector_type(2)));
typedef __fp16 fp16x2 __attribute__((ext_vector_type(2)));
typedef float f32x4 __attribute__((ext_vector_type(4)));
typedef unsigned u32x4 __attribute__((ext_vector_type(4)));

__device__ __forceinline__ unsigned pk16(float lo, float hi) {
  fp16x2 r = __builtin_amdgcn_cvt_pkrtz(lo, hi);
  return __builtin_bit_cast(unsigned, r);
}
__device__ __forceinline__ float fast_tanh(float x) {
  float e = __expf(2.f * x);
  return 1.f - 2.f / (e + 1.f);
}
}  // namespace

extern "C" __global__ void __launch_bounds__(512, 2)
seq_main(const int* __restrict__ inputs, const int* __restrict__ targets,
         const int* __restrict__ task_ids, const float* __restrict__ st0,
         const float* __restrict__ bit_emb, const float* __restrict__ task_u,
         const float* __restrict__ ctx_emb, const float* __restrict__ rw_g,
         const float* __restrict__ rb_g, const float* __restrict__ Wq_g,
         const float* __restrict__ Wc_g, const float* __restrict__ b_g,
         const float* __restrict__ A_g, float* __restrict__ wsout) {
  const int tid = threadIdx.x, blk = blockIdx.x;
  const int l = tid & 63, w = tid >> 6;
  const int b = l & 15, g4 = l >> 4;
  const int i0 = 16 * w + 4 * g4;     // owned i-range (with b): i0..i0+3
  const int dw0 = 8 * w + 2 * g4;     // fp16-dword index of i0

  __shared__ __align__(16) unsigned q16_l[2][16][68];
  __shared__ __align__(16) unsigned tq_l[2][16][68];
  __shared__ __align__(16) unsigned p16_l[16][68];
  __shared__ __align__(16) unsigned s16_l[16][16];
  __shared__ __align__(16) unsigned rw16_l[32][148];
  __shared__ __align__(16) float u4_l[4][128];
  __shared__ __align__(16) float chartw_l[16][12];
  __shared__ __align__(16) float cwnext_l[16][12];
  __shared__ float rb_l[32];
  __shared__ int sel_l[32][16];
  __shared__ int task_l[32][16];
  __shared__ int tgt_l[32][16];
  __shared__ float lk_l[16][36];
  __shared__ float scw_l[32];
  __shared__ float scnt_l[4];

  // ---------------- init staging ----------------
  if (tid < 32) scw_l[tid] = 0.f;
  if (tid < 4) scnt_l[tid] = 0.f;
  if (tid < 32) rb_l[tid] = rb_g[tid];
  {  // per-(t,b) ints: 512 = 32t x 16b
    int t = tid >> 4, bb = tid & 15;
    int gb = blk * 16 + bb;
    int bit = inputs[gb * kT + t];
    int task = task_ids[gb * kT + t];
    sel_l[t][bb] = task * 2 + bit;
    task_l[t][bb] = task;
    tgt_l[t][bb] = targets[gb * kT + t];
  }
  {  // u table: 512 = 4 combos x 128
    int cb = tid >> 7, i = tid & 127;
    u4_l[cb][i] = tanhf(bit_emb[(cb & 1) * kDQ + i]) + tanhf(task_u[(cb >> 1) * kDQ + i]);
  }
  for (int idx = tid; idx < 32 * 148; idx += 512) {  // rw fp16, K padded to 288
    int pr = idx / 148, dw = idx - pr * 148;
    int d0 = 2 * dw;
    float lo = (d0 < 257) ? rw_g[pr * 257 + d0] : 0.f;
    float hi = (d0 + 1 < 257) ? rw_g[pr * 257 + d0 + 1] : 0.f;
    rw16_l[pr][dw] = pk16(lo, hi);
  }
  if (tid < 256) {  // s-slice of state (d=256), zero-padded
    int bb = tid >> 4, dw = tid & 15;
    s16_l[bb][dw] = (dw == 0) ? pk16(st0[(blk * 16 + bb) * kD + 256], 0.f) : 0u;
  }

  // ---------------- A fragments (fp16) in regs: tile k, rows=i_local ----------------
  u32x4 afr[8][4];
  #pragma unroll
  for (int k = 0; k < 8; ++k) {
    #pragma unroll
    for (int ks = 0; ks < 4; ++ks) {
      const float* ap = A_g + ((size_t)(k * kDQ + 16 * w + b)) * kDQ + 32 * ks + 8 * g4;
      float4 fa = *(const float4*)ap;
      float4 fb = *(const float4*)(ap + 4);
      u32x4 v;
      v.x = pk16(fa.x, fa.y); v.y = pk16(fa.z, fa.w);
      v.z = pk16(fb.x, fb.y); v.w = pk16(fb.z, fb.w);
      afr[k][ks] = v;
    }
  }
  // Wq^T fragments (rows=k, 8 valid of 16)
  u32x4 wqf[4];
  #pragma unroll
  for (int ks = 0; ks < 4; ++ks) {
    float e_[8];
    #pragma unroll
    for (int e = 0; e < 8; ++e)
      e_[e] = (b < 8) ? Wq_g[(32 * ks + 8 * g4 + e) * kK + b] : 0.f;
    u32x4 v;
    v.x = pk16(e_[0], e_[1]); v.y = pk16(e_[2], e_[3]);
    v.z = pk16(e_[4], e_[5]); v.w = pk16(e_[6], e_[7]);
    wqf[ks] = v;
  }
  // ctx terms per lane (k = 4*g4 + r)
  float ctx0[4], ctx1[4];
  #pragma unroll
  for (int r = 0; r < 4; ++r) {
    int k = 4 * g4 + r;
    float s0v = 0.f, s1v = 0.f;
    if (k < 8) {
      s0v = b_g[k]; s1v = b_g[k];
      #pragma unroll
      for (int c = 0; c < kCTX; ++c) {
        float wc = Wc_g[c * kK + k];
        s0v += tanhf(ctx_emb[c]) * wc;
        s1v += tanhf(ctx_emb[kCTX + c]) * wc;
      }
    }
    ctx0[r] = s0v; ctx1[r] = s1v;
  }
  // persistent state in regs: (b, i0..i0+3)
  float q[4], p[4];
  {
    const int gb = blk * 16 + b;
    #pragma unroll
    for (int r = 0; r < 4; ++r) {
      q[r] = st0[gb * kD + i0 + r];
      p[r] = st0[gb * kD + kDQ + i0 + r];
    }
  }
  q16_l[0][b][dw0] = pk16(q[0], q[1]);
  q16_l[0][b][dw0 + 1] = pk16(q[2], q[3]);
  tq_l[0][b][dw0] = pk16(fast_tanh(q[0]), fast_tanh(q[1]));
  tq_l[0][b][dw0 + 1] = pk16(fast_tanh(q[2]), fast_tanh(q[3]));

  // tail accumulators (wave 2 lanes 0-15 use them)
  float aF = 0.f, aC = 0.f, aPE = 0.f;
  float aU[8] = {0.f, 0.f, 0.f, 0.f, 0.f, 0.f, 0.f, 0.f};
  float aTS0 = 0.f, aTS1 = 0.f, aTC0 = 0.f, aTC1 = 0.f;

  float w8[8];

  // ---- R phase: router MFMA + in-reg softmax + bpermute distribution ----
  auto runR = [&](int step) {
    const int nb_ = (step + 1) & 1;
    int snx = step + 1; if (snx > 255) snx = 255;
    const int tn = task_l[snx >> 3][b];
    f32x4 wacc = {0.f, 0.f, 0.f, 0.f};
    #pragma unroll
    for (int ks = 0; ks < 4; ++ks) {
      u32x4 bq = *(const u32x4*)&q16_l[nb_][b][ks * 16 + 4 * g4];
      wacc = __builtin_amdgcn_mfma_f32_16x16x32_f16(
          __builtin_bit_cast(half8, wqf[ks]), __builtin_bit_cast(half8, bq), wacc, 0, 0, 0);
    }
    float lg[4];
    #pragma unroll
    for (int r = 0; r < 4; ++r) lg[r] = wacc[r] + (tn ? ctx1[r] : ctx0[r]);
    float m = fmaxf(fmaxf(lg[0], lg[1]), fmaxf(lg[2], lg[3]));
    m = fmaxf(m, __shfl_xor(m, 16));
    float e0 = __expf(lg[0] - m), e1 = __expf(lg[1] - m);
    float e2 = __expf(lg[2] - m), e3 = __expf(lg[3] - m);
    float s = e0 + e1 + e2 + e3;
    s += __shfl_xor(s, 16);
    float inv = 1.f / s;
    float w0 = e0 * inv, w1 = e1 * inv, w2 = e2 * inv, w3 = e3 * inv;
    if (step >= 0 && (step & 7) == 6 && w == 3 && g4 < 2) {
      f32x4 cv = {w0, w1, w2, w3};
      *(f32x4*)&chartw_l[b][4 * g4] = cv;   // chart_w = ws[-1]
    }
    if (step >= 0 && (step & 7) == 7) {     // chart_w_next with CURRENT t's ctx
      const int tc = task_l[step >> 3][b];
      float lh[4];
      #pragma unroll
      for (int r = 0; r < 4; ++r) lh[r] = wacc[r] + (tc ? ctx1[r] : ctx0[r]);
      float m2 = fmaxf(fmaxf(lh[0], lh[1]), fmaxf(lh[2], lh[3]));
      m2 = fmaxf(m2, __shfl_xor(m2, 16));
      float f0 = __expf(lh[0] - m2), f1 = __expf(lh[1] - m2);
      float f2 = __expf(lh[2] - m2), f3 = __expf(lh[3] - m2);
      float s2 = f0 + f1 + f2 + f3;
      s2 += __shfl_xor(s2, 16);
      float i2 = 1.f / s2;
      if (w == 3 && g4 < 2) {
        f32x4 cv = {f0 * i2, f1 * i2, f2 * i2, f3 * i2};
        *(f32x4*)&cwnext_l[b][4 * g4] = cv;
      }
    }
    // distribute w[b][k] to every lane of its b (fp16-packed, 4 bpermutes)
    int pk01 = (int)pk16(w0, w1), pk23 = (int)pk16(w2, w3);
    int alo = 4 * b, ahi = 4 * (16 + b);
    int r01l = __builtin_amdgcn_ds_bpermute(alo, pk01);
    int r23l = __builtin_amdgcn_ds_bpermute(alo, pk23);
    int r01h = __builtin_amdgcn_ds_bpermute(ahi, pk01);
    int r23h = __builtin_amdgcn_ds_bpermute(ahi, pk23);
    h2 v;
    v = __builtin_bit_cast(h2, r01l); w8[0] = (float)v.x; w8[1] = (float)v.y;
    v = __builtin_bit_cast(h2, r23l); w8[2] = (float)v.x; w8[3] = (float)v.y;
    v = __builtin_bit_cast(h2, r01h); w8[4] = (float)v.x; w8[5] = (float)v.y;
    v = __builtin_bit_cast(h2, r23h); w8[6] = (float)v.x; w8[7] = (float)v.y;
  };

  // ---- decode: logits_k = state16 . rw16 (always reads q16 buf 0) ----
  auto runDecode = [&]() {
    const int pair = 16 * w + b;  // wave 0 -> pairs 0-15, wave 1 -> 16-31
    f32x4 dacc = {0.f, 0.f, 0.f, 0.f};
    #pragma unroll
    for (int ks = 0; ks < 4; ++ks) {
      u32x4 aq = *(const u32x4*)&q16_l[0][b][ks * 16 + 4 * g4];
      u32x4 bq = *(const u32x4*)&rw16_l[pair][ks * 16 + 4 * g4];
      dacc = __builtin_amdgcn_mfma_f32_16x16x32_f16(
          __builtin_bit_cast(half8, aq), __builtin_bit_cast(half8, bq), dacc, 0, 0, 0);
    }
    #pragma unroll
    for (int ks = 4; ks < 8; ++ks) {
      u32x4 aq = *(const u32x4*)&p16_l[b][(ks - 4) * 16 + 4 * g4];
      u32x4 bq = *(const u32x4*)&rw16_l[pair][ks * 16 + 4 * g4];
      dacc = __builtin_amdgcn_mfma_f32_16x16x32_f16(
          __builtin_bit_cast(half8, aq), __builtin_bit_cast(half8, bq), dacc, 0, 0, 0);
    }
    {
      u32x4 aq = *(const u32x4*)&s16_l[b][4 * g4];
      u32x4 bq = *(const u32x4*)&rw16_l[pair][128 + 4 * g4];
      dacc = __builtin_amdgcn_mfma_f32_16x16x32_f16(
          __builtin_bit_cast(half8, aq), __builtin_bit_cast(half8, bq), dacc, 0, 0, 0);
    }
    #pragma unroll
    for (int r = 0; r < 4; ++r) lk_l[4 * g4 + r][pair] = dacc[r];
  };

  // ---- tail: per-batch scalar losses/stats (wave 2, lanes 0-15) ----
  auto runTail = [&](int t) {
    if (l >= 16) return;
    const int bb = l;
    const int tgt = tgt_l[t][bb];
    const int task = task_l[t][bb];
    const int prv = (t == 0) ? 0 : tgt_l[t - 1][bb];
    f32x4 ca = *(const f32x4*)&cwnext_l[bb][0];
    f32x4 cbv = *(const f32x4*)&cwnext_l[bb][4];
    float cw[8] = {ca.x, ca.y, ca.z, ca.w, cbv.x, cbv.y, cbv.z, cbv.w};
    f32x4 ha = *(const f32x4*)&chartw_l[bb][0];
    f32x4 hb = *(const f32x4*)&chartw_l[bb][4];
    float ch[8] = {ha.x, ha.y, ha.z, ha.w, hb.x, hb.y, hb.z, hb.w};
    // top-2 (first-occurrence ties)
    int i0_ = 0; float v0 = cw[0];
    #pragma unroll
    for (int kk = 1; kk < 8; ++kk) if (cw[kk] > v0) { v0 = cw[kk]; i0_ = kk; }
    int i1_ = (i0_ == 0) ? 1 : 0;
    float v1 = (i0_ == 0) ? cw[1] : cw[0];
    #pragma unroll
    for (int kk = 0; kk < 8; ++kk) if (kk != i0_ && cw[kk] > v1) { v1 = cw[kk]; i1_ = kk; }
    float wsum = fmaxf(v0 + v1, kEPS);
    float wn0 = v0 / wsum, wn1 = v1 / wsum;
    float lg4[4];
    #pragma unroll
    for (int v = 0; v < 4; ++v)
      lg4[v] = wn0 * (lk_l[bb][i0_ * 4 + v] + rb_l[i0_ * 4 + v]) +
               wn1 * (lk_l[bb][i1_ * 4 + v] + rb_l[i1_ * 4 + v]);
    float m2 = fmaxf(lg4[0], lg4[1]);
    float lse2 = m2 + logf(expf(lg4[0] - m2) + expf(lg4[1] - m2));
    float m4 = fmaxf(fmaxf(lg4[0], lg4[1]), fmaxf(lg4[2], lg4[3]));
    float lse4 = m4 + logf(expf(lg4[0] - m4) + expf(lg4[1] - m4) +
                           expf(lg4[2] - m4) + expf(lg4[3] - m4));
    int idx2 = (tgt < 1) ? tgt : 1;
    float p2 = (idx2 == 0) ? lg4[0] : lg4[1];
    float p4v = (tgt == 0) ? lg4[0] : ((tgt == 1) ? lg4[1] : ((tgt == 2) ? lg4[2] : lg4[3]));
    float ce2 = lse2 - p2, ce4 = lse4 - p4v;
    float pe = (task == 0) ? ce2 : ce4;
    int pred;
    if (task == 0) pred = (lg4[1] > lg4[0]) ? 1 : 0;
    else {
      pred = 0; float bv = lg4[0];
      if (lg4[1] > bv) { bv = lg4[1]; pred = 1; }
      if (lg4[2] > bv) { bv = lg4[2]; pred = 2; }
      if (lg4[3] > bv) { bv = lg4[3]; pred = 3; }
    }
    float corr = (pred == tgt) ? 1.f : 0.f;
    float chprv = chartw_l[bb][prv];  // LDS read avoids runtime reg-index
    float csl = -logf(fmaxf(chprv, kEPS));
    float Ft = kGAMMA * (pe + csl);
    aF += Ft; aC += corr; aPE += pe;
    #pragma unroll
    for (int kk = 0; kk < 8; ++kk) aU[kk] += ch[kk];
    if (task == 0) { aTS0 += corr; aTC0 += 1.f; }
    else {
      aTS1 += corr; aTC1 += 1.f;
      #pragma unroll
      for (int kk = 0; kk < 8; ++kk) atomicAdd(&scw_l[prv * 8 + kk], ch[kk]);
      atomicAdd(&scnt_l[prv], 1.f);
    }
  };

  __syncthreads();
  runR(-1);  // w for step 0

  float u_own[4] = {0.f, 0.f, 0.f, 0.f};
  #pragma unroll 1
  for (int step = 0; step < 256; ++step) {
    const int cb_ = step & 1, nb_ = cb_ ^ 1;
    const int e = step & 7, t = step >> 3;
    if (e == 0) {
      int sel = sel_l[t][b];
      f32x4 uu = *(const f32x4*)&u4_l[sel][i0];
      u_own[0] = uu.x; u_own[1] = uu.y; u_own[2] = uu.z; u_own[3] = uu.w;
    }
    // ---- X: force MFMA (16 batch cols), combine, update ----
    f32x4 ac[8];
    #pragma unroll
    for (int k = 0; k < 8; ++k) ac[k] = f32x4{0.f, 0.f, 0.f, 0.f};
    #pragma unroll
    for (int ks = 0; ks < 4; ++ks) {
      u32x4 bq = *(const u32x4*)&tq_l[cb_][b][ks * 16 + 4 * g4];
      half8 bf = __builtin_bit_cast(half8, bq);
      #pragma unroll
      for (int k = 0; k < 8; ++k)
        ac[k] = __builtin_amdgcn_mfma_f32_16x16x32_f16(
            __builtin_bit_cast(half8, afr[k][ks]), bf, ac[k], 0, 0, 0);
    }
    #pragma unroll
    for (int r = 0; r < 4; ++r) {
      float f = w8[0] * ac[0][r] + w8[1] * ac[1][r] + w8[2] * ac[2][r] + w8[3] * ac[3][r] +
                w8[4] * ac[4][r] + w8[5] * ac[5][r] + w8[6] * ac[6][r] + w8[7] * ac[7][r];
      float pn = (1.f - kDT * kDAMP) * p[r] + kDT * (f + u_own[r]);
      q[r] += kDT * fast_tanh(pn);
      p[r] = pn;
    }
    q16_l[nb_][b][dw0] = pk16(q[0], q[1]);
    q16_l[nb_][b][dw0 + 1] = pk16(q[2], q[3]);
    tq_l[nb_][b][dw0] = pk16(fast_tanh(q[0]), fast_tanh(q[1]));
    tq_l[nb_][b][dw0 + 1] = pk16(fast_tanh(q[2]), fast_tanh(q[3]));
    if (e == 7) {
      p16_l[b][dw0] = pk16(p[0], p[1]);
      p16_l[b][dw0 + 1] = pk16(p[2], p[3]);
    }
    if (e == 0 && step != 0 && w < 2) runDecode();      // decode prev t's state
    if (e == 1 && step > 8 && w == 2) runTail(t - 1);   // tail one step later
    __syncthreads();
    runR(step);  // w for step+1 (+ chartw/cwnext at e6/e7)
  }

  __syncthreads();
  if (w < 2) runDecode();   // t = 31
  __syncthreads();
  if (w == 2) runTail(31);
  __syncthreads();

  if (w == 2) {
    float vF = aF, vC = aC, vPE = aPE;
    float vTS0 = aTS0, vTS1 = aTS1, vTC0 = aTC0, vTC1 = aTC1;
    float vU[8];
    #pragma unroll
    for (int kk = 0; kk < 8; ++kk) vU[kk] = aU[kk];
    #pragma unroll
    for (int d = 1; d < 16; d <<= 1) {
      vF += __shfl_xor(vF, d); vC += __shfl_xor(vC, d); vPE += __shfl_xor(vPE, d);
      vTS0 += __shfl_xor(vTS0, d); vTS1 += __shfl_xor(vTS1, d);
      vTC0 += __shfl_xor(vTC0, d); vTC1 += __shfl_xor(vTC1, d);
      #pragma unroll
      for (int kk = 0; kk < 8; ++kk) vU[kk] += __shfl_xor(vU[kk], d);
    }
    if (l == 0) {
      float* wo = wsout + blk * 64;
      wo[0] = vF; wo[1] = vC; wo[2] = vPE;
      #pragma unroll
      for (int kk = 0; kk < 8; ++kk) wo[3 + kk] = vU[kk];
      wo[11] = vTS0; wo[12] = vTS1; wo[13] = vTC0; wo[14] = vTC1;
    }
    if (l < 32) wsout[blk * 64 + 15 + l] = scw_l[l];
    if (l < 4) wsout[blk * 64 + 47 + l] = scnt_l[l];
  }
}

extern "C" __global__ void seq_finalize(const float* __restrict__ ws, float* __restrict__ out) {
  const int tid = threadIdx.x;
  __shared__ float red[51];
  if (tid < 51) {
    float s = 0.f;
    for (int blk = 0; blk < 16; ++blk) s += ws[blk * 64 + tid];
    red[tid] = s;
  }
  __syncthreads();
  if (tid == 0) {
    const float BT = 256.f * 32.f;
    out[0] = red[0] / BT;
    out[1] = red[1] / BT;
    out[2] = red[2] / BT;
    float us = 0.f;
    for (int k = 0; k < 8; k++) { out[3 + k] = red[3 + k]; us += red[3 + k]; }
    float ent = 0.f;
    for (int k = 0; k < 8; k++) {
      float dist = red[3 + k] / (us + kEPS);
      ent -= dist * logf(dist + kEPS);
    }
    out[11] = ent;
    out[12] = red[11] / (red[13] + kEPS);
    out[13] = red[12] / (red[14] + kEPS);
    float tot = 0.f;
    for (int j = 0; j < 32; j++) { out[14 + j] = red[15 + j]; tot += red[15 + j]; }
    for (int s2 = 0; s2 < 4; s2++) out[46 + s2] = red[47 + s2];
    float inv = 1.f / (tot + kEPS);
    float ps[4] = {0.f, 0.f, 0.f, 0.f};
    float pc[8] = {0.f, 0.f, 0.f, 0.f, 0.f, 0.f, 0.f, 0.f};
    for (int s2 = 0; s2 < 4; s2++)
      for (int k = 0; k < 8; k++) {
        float jv = red[15 + s2 * 8 + k] * inv;
        ps[s2] += jv; pc[k] += jv;
      }
    float mi = 0.f;
    for (int s2 = 0; s2 < 4; s2++)
      for (int k = 0; k < 8; k++) {
        float jv = red[15 + s2 * 8 + k] * inv;
        mi += jv * (logf(jv + kEPS) - logf(ps[s2] + kEPS) - logf(pc[k] + kEPS));
      }
    mi = (tot > 0.f) ? fmaxf(mi, 0.f) : 0.f;
    out[50] = mi;
  }
}

extern "C" void kernel_launch(void* const* d_in, const int* in_sizes, int n_in,
                              void* d_out, int out_size, void* d_ws, size_t ws_size,
                              hipStream_t stream) {
  (void)in_sizes; (void)n_in; (void)out_size; (void)ws_size;
  const int* inputs   = (const int*)d_in[0];
  const int* targets  = (const int*)d_in[1];
  const int* task_ids = (const int*)d_in[2];
  const float* st0      = (const float*)d_in[3];
  const float* bit_emb  = (const float*)d_in[4];
  const float* task_u   = (const float*)d_in[5];
  const float* ctx_emb  = (const float*)d_in[6];
  const float* rw       = (const float*)d_in[7];
  const float* rb       = (const float*)d_in[8];
  const float* Wq       = (const float*)d_in[9];
  const float* Wc       = (const float*)d_in[10];
  const float* bb       = (const float*)d_in[11];
  const float* A        = (const float*)d_in[12];
  float* ws  = (float*)d_ws;
  float* out = (float*)d_out;
  hipLaunchKernelGGL(seq_main, dim3(16), dim3(512), 0, stream,
                     inputs, targets, task_ids, st0, bit_emb, task_u, ctx_emb,
                     rw, rb, Wq, Wc, bb, A, ws);
  hipLaunchKernelGGL(seq_finalize, dim3(1), dim3(64), 0, stream, ws, out);
}